// Round 1
// baseline (114.660 us; speedup 1.0000x reference)
//
#include <hip/hip_runtime.h>

// Problem constants (from the reference):
//   B = 16384 features rows, D = 256, M = 262144 memory slots, memory_index = device int
constexpr int B  = 16384;
constexpr int D  = 256;
constexpr int M  = 262144;
constexpr int D4 = D / 4;      // 64 float4 per row
constexpr int LOG_D4 = 6;

constexpr int UTIL_BLOCKS  = 256;
constexpr int UTIL_THREADS = 256;

// ---------------------------------------------------------------------------
// Kernel 1: new_mem = memory_attentions with rows (mi + i) % M, i in [0,B),
// replaced by features[i]. float4 grid-stride copy; a wave of 64 lanes covers
// exactly one 256-float row, so the feat/mem branch is wave-uniform.
// ---------------------------------------------------------------------------
__global__ __launch_bounds__(256) void mem_kernel(
    const float4* __restrict__ mem,
    const float4* __restrict__ feat,
    const int*    __restrict__ mi_p,
    float4*       __restrict__ out)
{
    const int s = ((*mi_p) % M + M) % M;
    const int total  = M * D4;                    // 2^24 float4s
    const int stride = gridDim.x * blockDim.x;
    for (int v = blockIdx.x * blockDim.x + threadIdx.x; v < total; v += stride) {
        const int row = v >> LOG_D4;
        int rel = row - s;
        if (rel < 0) rel += M;
        float4 val;
        if (rel < B) {
            val = feat[(rel << LOG_D4) | (v & (D4 - 1))];
        } else {
            val = mem[v];
        }
        out[v] = val;
    }
}

// ---------------------------------------------------------------------------
// Kernel 2: new_util = memory_utilities with the circular range set to
// attention_quality. Fused: per-block partial sums of new_util[i] for
// i < new_index (deterministic fixed-shape reduction).
// ---------------------------------------------------------------------------
__global__ __launch_bounds__(UTIL_THREADS) void util_kernel(
    const float4* __restrict__ util,
    const float*  __restrict__ aq_p,
    const int*    __restrict__ mi_p,
    float4*       __restrict__ out_util,
    float*        __restrict__ block_sums)
{
    const int mi   = *mi_p;
    const int s    = (mi % M + M) % M;
    const int nidx = (mi + B) % M;
    const float aq = *aq_p;

    const int tid      = blockIdx.x * blockDim.x + threadIdx.x;
    const int nthreads = gridDim.x * blockDim.x;

    float local = 0.f;
    for (int i4 = tid; i4 < M / 4; i4 += nthreads) {
        const float4 u = util[i4];
        const float in4[4] = {u.x, u.y, u.z, u.w};
        float out4[4];
        const int base = i4 * 4;
#pragma unroll
        for (int j = 0; j < 4; ++j) {
            const int i = base + j;
            int rel = i - s;
            if (rel < 0) rel += M;
            const float v = (rel < B) ? aq : in4[j];
            out4[j] = v;
            if (i < nidx) local += v;
        }
        out_util[i4] = make_float4(out4[0], out4[1], out4[2], out4[3]);
    }

    // wave(64) butterfly reduce, then LDS across the 4 waves of the block
    for (int off = 32; off > 0; off >>= 1)
        local += __shfl_down(local, off, 64);
    __shared__ float wsum[UTIL_THREADS / 64];
    const int lane = threadIdx.x & 63;
    const int wid  = threadIdx.x >> 6;
    if (lane == 0) wsum[wid] = local;
    __syncthreads();
    if (threadIdx.x == 0) {
        float s2 = 0.f;
#pragma unroll
        for (int w = 0; w < UTIL_THREADS / 64; ++w) s2 += wsum[w];
        block_sums[blockIdx.x] = s2;
    }
}

// ---------------------------------------------------------------------------
// Kernel 3: reduce the 256 block sums; write utilization and quality.
// ---------------------------------------------------------------------------
__global__ __launch_bounds__(256) void finalize_kernel(
    const float* __restrict__ block_sums,
    const int*   __restrict__ mi_p,
    float*       __restrict__ out_scalars)   // [utilization, quality]
{
    const int  mi   = *mi_p;
    const int  nidx = (mi + B) % M;
    const bool full = (mi + B) >= M;

    float v = (threadIdx.x < UTIL_BLOCKS) ? block_sums[threadIdx.x] : 0.f;
    for (int off = 32; off > 0; off >>= 1)
        v += __shfl_down(v, off, 64);
    __shared__ float wsum[4];
    if ((threadIdx.x & 63) == 0) wsum[threadIdx.x >> 6] = v;
    __syncthreads();
    if (threadIdx.x == 0) {
        const float sum = wsum[0] + wsum[1] + wsum[2] + wsum[3];
        out_scalars[0] = full ? 1.0f : (float)nidx / (float)M;
        out_scalars[1] = sum / (float)nidx;
    }
}

// ---------------------------------------------------------------------------
extern "C" void kernel_launch(void* const* d_in, const int* in_sizes, int n_in,
                              void* d_out, int out_size, void* d_ws, size_t ws_size,
                              hipStream_t stream)
{
    const float* feat = (const float*)d_in[0];   // (B, D) f32
    const float* aq   = (const float*)d_in[1];   // scalar f32
    const float* mem  = (const float*)d_in[2];   // (M, D) f32
    const float* util = (const float*)d_in[3];   // (M,) f32
    const int*   mi   = (const int*)  d_in[4];   // scalar int

    float* out         = (float*)d_out;
    float* out_mem     = out;                            // M*D
    float* out_util    = out + (size_t)M * D;            // M
    float* out_scalars = out_util + M;                   // [utilization, quality]
    float* block_sums  = (float*)d_ws;                   // UTIL_BLOCKS floats

    // Big copy: 2^24 float4s, grid-stride over 2048 blocks (memory-bound cap).
    mem_kernel<<<2048, 256, 0, stream>>>(
        (const float4*)mem, (const float4*)feat, mi, (float4*)out_mem);

    util_kernel<<<UTIL_BLOCKS, UTIL_THREADS, 0, stream>>>(
        (const float4*)util, aq, mi, (float4*)out_util, block_sums);

    finalize_kernel<<<1, 256, 0, stream>>>(block_sums, mi, out_scalars);
}

// Round 2
// 104.458 us; speedup vs baseline: 1.0977x; 1.0977x over previous
//
#include <hip/hip_runtime.h>

// Problem constants (from the reference):
//   B = 16384 features rows, D = 256, M = 262144 memory slots
constexpr int B  = 16384;
constexpr int D  = 256;
constexpr int M  = 262144;
constexpr int D4 = D / 4;      // 64 float4 per row
constexpr int LOG_D4 = 6;

typedef float f32x4 __attribute__((ext_vector_type(4)));

constexpr int THREADS    = 256;
constexpr int MEM_BLOCKS = 2048;                    // 8 blocks/CU on 256 CUs
constexpr int TOTAL4     = M * D4;                  // 2^24 float4
constexpr int STRIDE     = MEM_BLOCKS * THREADS;    // 524288
constexpr int ITERS      = TOTAL4 / STRIDE;         // 32 (exact)
constexpr int BATCH      = 4;

constexpr int UTIL_BLOCKS = 256;                    // 256*256 threads = M/4 float4s

// ---------------------------------------------------------------------------
// Fused kernel:
//  - all blocks: streaming copy of new_mem (rows [s, s+B) mod M from feat,
//    rest from mem). 4 loads in flight per wave, nontemporal policy.
//  - first UTIL_BLOCKS blocks additionally produce new_util (1 float4/thread)
//    and per-block partial sums of new_util[:new_index].
// ---------------------------------------------------------------------------
__global__ __launch_bounds__(THREADS) void fused_kernel(
    const f32x4* __restrict__ mem,
    const f32x4* __restrict__ feat,
    const f32x4* __restrict__ util,
    const float* __restrict__ aq_p,
    const int*   __restrict__ mi_p,
    f32x4*       __restrict__ out_mem,
    f32x4*       __restrict__ out_util,
    float*       __restrict__ block_sums)
{
    const int s = ((*mi_p) % M + M) % M;

    // ---- util part first (256 blocks, tiny) so it overlaps the stream ----
    if (blockIdx.x < UTIL_BLOCKS) {
        const int   mi   = *mi_p;
        const int   nidx = (mi + B) % M;
        const float aq   = *aq_p;
        const int   i4   = blockIdx.x * THREADS + threadIdx.x;  // 0 .. M/4-1
        const f32x4 u    = util[i4];
        f32x4 o;
        float local = 0.f;
        const int base = i4 * 4;
#pragma unroll
        for (int j = 0; j < 4; ++j) {
            const int i = base + j;
            int rel = i - s;
            if (rel < 0) rel += M;
            const float v = (rel < B) ? aq : u[j];
            o[j] = v;
            if (i < nidx) local += v;
        }
        out_util[i4] = o;

        for (int off = 32; off > 0; off >>= 1)
            local += __shfl_down(local, off, 64);
        __shared__ float wsum[THREADS / 64];
        const int lane = threadIdx.x & 63;
        const int wid  = threadIdx.x >> 6;
        if (lane == 0) wsum[wid] = local;
        __syncthreads();
        if (threadIdx.x == 0) {
            float s2 = 0.f;
#pragma unroll
            for (int w = 0; w < THREADS / 64; ++w) s2 += wsum[w];
            block_sums[blockIdx.x] = s2;
        }
    }

    // ---- big streaming copy: exactly ITERS iterations, batched 4-wide ----
    const int tid = blockIdx.x * THREADS + threadIdx.x;
    for (int it = 0; it < ITERS; it += BATCH) {
        f32x4 vals[BATCH];
#pragma unroll
        for (int j = 0; j < BATCH; ++j) {
            const int v   = tid + (it + j) * STRIDE;
            const int row = v >> LOG_D4;
            int rel = row - s;
            if (rel < 0) rel += M;
            if (rel < B) {
                vals[j] = feat[(rel << LOG_D4) | (v & (D4 - 1))];
            } else {
                vals[j] = __builtin_nontemporal_load(&mem[v]);
            }
        }
#pragma unroll
        for (int j = 0; j < BATCH; ++j) {
            const int v = tid + (it + j) * STRIDE;
            __builtin_nontemporal_store(vals[j], &out_mem[v]);
        }
    }
}

// ---------------------------------------------------------------------------
// Finalize: reduce the 256 block sums; write utilization and quality.
// ---------------------------------------------------------------------------
__global__ __launch_bounds__(256) void finalize_kernel(
    const float* __restrict__ block_sums,
    const int*   __restrict__ mi_p,
    float*       __restrict__ out_scalars)   // [utilization, quality]
{
    const int  mi   = *mi_p;
    const int  nidx = (mi + B) % M;
    const bool full = (mi + B) >= M;

    float v = (threadIdx.x < UTIL_BLOCKS) ? block_sums[threadIdx.x] : 0.f;
    for (int off = 32; off > 0; off >>= 1)
        v += __shfl_down(v, off, 64);
    __shared__ float wsum[4];
    if ((threadIdx.x & 63) == 0) wsum[threadIdx.x >> 6] = v;
    __syncthreads();
    if (threadIdx.x == 0) {
        const float sum = wsum[0] + wsum[1] + wsum[2] + wsum[3];
        out_scalars[0] = full ? 1.0f : (float)nidx / (float)M;
        out_scalars[1] = sum / (float)nidx;
    }
}

// ---------------------------------------------------------------------------
extern "C" void kernel_launch(void* const* d_in, const int* in_sizes, int n_in,
                              void* d_out, int out_size, void* d_ws, size_t ws_size,
                              hipStream_t stream)
{
    const float* feat = (const float*)d_in[0];   // (B, D) f32
    const float* aq   = (const float*)d_in[1];   // scalar f32
    const float* mem  = (const float*)d_in[2];   // (M, D) f32
    const float* util = (const float*)d_in[3];   // (M,) f32
    const int*   mi   = (const int*)  d_in[4];   // scalar int

    float* out         = (float*)d_out;
    float* out_mem     = out;                    // M*D
    float* out_util    = out + (size_t)M * D;    // M
    float* out_scalars = out_util + M;           // [utilization, quality]
    float* block_sums  = (float*)d_ws;           // UTIL_BLOCKS floats

    fused_kernel<<<MEM_BLOCKS, THREADS, 0, stream>>>(
        (const f32x4*)mem, (const f32x4*)feat, (const f32x4*)util,
        aq, mi, (f32x4*)out_mem, (f32x4*)out_util, block_sums);

    finalize_kernel<<<1, 256, 0, stream>>>(block_sums, mi, out_scalars);
}

// Round 3
// 96.443 us; speedup vs baseline: 1.1889x; 1.0831x over previous
//
#include <hip/hip_runtime.h>

// Problem constants (from the reference):
//   B = 16384 features rows, D = 256, M = 262144 memory slots
constexpr int B  = 16384;
constexpr int D  = 256;
constexpr int M  = 262144;
constexpr int D4 = D / 4;      // 64 float4 per row
constexpr int LOG_D4 = 6;

typedef float f32x4 __attribute__((ext_vector_type(4)));

constexpr int THREADS    = 256;
constexpr int MEM_BLOCKS = 2048;                    // 8 blocks/CU on 256 CUs
constexpr int TOTAL4     = M * D4;                  // 2^24 float4
constexpr int STRIDE     = MEM_BLOCKS * THREADS;    // 524288 float4 = 8192 rows
constexpr int ROWSTRIDE  = STRIDE >> LOG_D4;        // 8192
constexpr int ITERS      = TOTAL4 / STRIDE;         // 32 (exact)
constexpr int BATCH      = 8;

constexpr int UTIL_BLOCKS = 256;                    // 256*256 threads = M/4 float4s

// ---------------------------------------------------------------------------
// Fused kernel:
//  - all blocks: streaming copy of new_mem (rows [s, s+B) mod M from feat,
//    rest from mem). 8 loads in flight per lane. Temporal loads (keep input
//    resident in L3 across replays), nontemporal stores (don't pollute L3
//    with the write-once output stream).
//  - first UTIL_BLOCKS blocks additionally produce new_util (1 float4/thread)
//    and per-block partial sums of new_util[:new_index].
// ---------------------------------------------------------------------------
__global__ __launch_bounds__(THREADS) void fused_kernel(
    const f32x4* __restrict__ mem,
    const f32x4* __restrict__ feat,
    const f32x4* __restrict__ util,
    const float* __restrict__ aq_p,
    const int*   __restrict__ mi_p,
    f32x4*       __restrict__ out_mem,
    f32x4*       __restrict__ out_util,
    float*       __restrict__ block_sums)
{
    const int s = ((*mi_p) % M + M) % M;

    // ---- util part first (256 blocks, tiny) so it overlaps the stream ----
    if (blockIdx.x < UTIL_BLOCKS) {
        const int   mi   = *mi_p;
        const int   nidx = (mi + B) % M;
        const float aq   = *aq_p;
        const int   i4   = blockIdx.x * THREADS + threadIdx.x;  // 0 .. M/4-1
        const f32x4 u    = util[i4];
        f32x4 o;
        float local = 0.f;
        const int base = i4 * 4;
#pragma unroll
        for (int j = 0; j < 4; ++j) {
            const int i = base + j;
            int rel = i - s;
            if (rel < 0) rel += M;
            const float v = (rel < B) ? aq : u[j];
            o[j] = v;
            if (i < nidx) local += v;
        }
        out_util[i4] = o;

        for (int off = 32; off > 0; off >>= 1)
            local += __shfl_down(local, off, 64);
        __shared__ float wsum[THREADS / 64];
        const int lane = threadIdx.x & 63;
        const int wid  = threadIdx.x >> 6;
        if (lane == 0) wsum[wid] = local;
        __syncthreads();
        if (threadIdx.x == 0) {
            float s2 = 0.f;
#pragma unroll
            for (int w = 0; w < THREADS / 64; ++w) s2 += wsum[w];
            block_sums[blockIdx.x] = s2;
        }
    }

    // ---- big streaming copy: exactly ITERS iterations, batched 8-wide ----
    const int tid  = blockIdx.x * THREADS + threadIdx.x;
    const int col  = tid & (D4 - 1);
    const int row0 = tid >> LOG_D4;
#pragma unroll
    for (int ib = 0; ib < ITERS / BATCH; ++ib) {
        f32x4 vals[BATCH];
#pragma unroll
        for (int j = 0; j < BATCH; ++j) {
            const int it  = ib * BATCH + j;
            const int row = row0 + it * ROWSTRIDE;
            int rel = row - s;
            if (rel < 0) rel += M;
            if (rel < B) {
                vals[j] = feat[(rel << LOG_D4) | col];
            } else {
                vals[j] = mem[tid + it * STRIDE];
            }
        }
#pragma unroll
        for (int j = 0; j < BATCH; ++j) {
            const int it = ib * BATCH + j;
            __builtin_nontemporal_store(vals[j], &out_mem[tid + it * STRIDE]);
        }
    }
}

// ---------------------------------------------------------------------------
// Finalize: reduce the 256 block sums; write utilization and quality.
// ---------------------------------------------------------------------------
__global__ __launch_bounds__(256) void finalize_kernel(
    const float* __restrict__ block_sums,
    const int*   __restrict__ mi_p,
    float*       __restrict__ out_scalars)   // [utilization, quality]
{
    const int  mi   = *mi_p;
    const int  nidx = (mi + B) % M;
    const bool full = (mi + B) >= M;

    float v = (threadIdx.x < UTIL_BLOCKS) ? block_sums[threadIdx.x] : 0.f;
    for (int off = 32; off > 0; off >>= 1)
        v += __shfl_down(v, off, 64);
    __shared__ float wsum[4];
    if ((threadIdx.x & 63) == 0) wsum[threadIdx.x >> 6] = v;
    __syncthreads();
    if (threadIdx.x == 0) {
        const float sum = wsum[0] + wsum[1] + wsum[2] + wsum[3];
        out_scalars[0] = full ? 1.0f : (float)nidx / (float)M;
        out_scalars[1] = sum / (float)nidx;
    }
}

// ---------------------------------------------------------------------------
extern "C" void kernel_launch(void* const* d_in, const int* in_sizes, int n_in,
                              void* d_out, int out_size, void* d_ws, size_t ws_size,
                              hipStream_t stream)
{
    const float* feat = (const float*)d_in[0];   // (B, D) f32
    const float* aq   = (const float*)d_in[1];   // scalar f32
    const float* mem  = (const float*)d_in[2];   // (M, D) f32
    const float* util = (const float*)d_in[3];   // (M,) f32
    const int*   mi   = (const int*)  d_in[4];   // scalar int

    float* out         = (float*)d_out;
    float* out_mem     = out;                    // M*D
    float* out_util    = out + (size_t)M * D;    // M
    float* out_scalars = out_util + M;           // [utilization, quality]
    float* block_sums  = (float*)d_ws;           // UTIL_BLOCKS floats

    fused_kernel<<<MEM_BLOCKS, THREADS, 0, stream>>>(
        (const f32x4*)mem, (const f32x4*)feat, (const f32x4*)util,
        aq, mi, (f32x4*)out_mem, (f32x4*)out_util, block_sums);

    finalize_kernel<<<1, 256, 0, stream>>>(block_sums, mi, out_scalars);
}

// Round 4
// 89.931 us; speedup vs baseline: 1.2750x; 1.0724x over previous
//
#include <hip/hip_runtime.h>

// Problem constants (from the reference):
//   B = 16384 features rows, D = 256, M = 262144 memory slots
constexpr int B  = 16384;
constexpr int D  = 256;
constexpr int M  = 262144;
constexpr int D4 = D / 4;      // 64 float4 per row
constexpr int LOG_D4 = 6;

typedef float f32x4 __attribute__((ext_vector_type(4)));

constexpr int THREADS    = 256;
constexpr int MEM_BLOCKS = 2048;                    // 8 blocks/CU on 256 CUs
constexpr int TOTAL4     = M * D4;                  // 2^24 float4
constexpr int STRIDE     = MEM_BLOCKS * THREADS;    // 524288 float4 = 8192 rows
constexpr int ROWSTRIDE  = STRIDE >> LOG_D4;        // 8192
constexpr int ITERS      = TOTAL4 / STRIDE;         // 32 (exact)
constexpr int BATCH      = 8;

constexpr int UTIL_BLOCKS = 256;                    // 256*256 threads = M/4 float4s

// ---------------------------------------------------------------------------
// Single fused kernel.
//  - All blocks: streaming copy of new_mem (rows [s, s+B) mod M from feat,
//    rest from mem). 8 loads in flight per lane; temporal loads, nt stores.
//  - Blocks [0, UTIL_BLOCKS): also write new_util (1 float4/thread). No
//    reduction needed anymore.
//  - Block MEM_BLOCKS-1: also computes the two scalars. Algebraic shortcut:
//    new_util[:nidx] = util_old[:s] ++ aq*B when the circular write range
//    [s, s+B) doesn't wrap, so quality = (sum(util[:s]) + B*aq)/(s+B) — a
//    s-element reduction (s=1000 here), done by one block, fixed order,
//    deterministic. Wrap case: prefix lies entirely inside the written
//    range -> quality = aq (or NaN for empty prefix, matching reference).
// ---------------------------------------------------------------------------
__global__ __launch_bounds__(THREADS) void fused_kernel(
    const f32x4* __restrict__ mem,
    const f32x4* __restrict__ feat,
    const f32x4* __restrict__ util4,
    const float* __restrict__ utilf,
    const float* __restrict__ aq_p,
    const int*   __restrict__ mi_p,
    f32x4*       __restrict__ out_mem,
    f32x4*       __restrict__ out_util,
    float*       __restrict__ out_scalars)
{
    const int s = ((*mi_p) % M + M) % M;

    if (blockIdx.x < UTIL_BLOCKS) {
        // ---- new_util write (1 MB total) ----
        const float aq = *aq_p;
        const int   i4 = blockIdx.x * THREADS + threadIdx.x;  // 0 .. M/4-1
        const f32x4 u  = util4[i4];
        f32x4 o;
        const int base = i4 * 4;
#pragma unroll
        for (int j = 0; j < 4; ++j) {
            const int i = base + j;
            int rel = i - s;
            if (rel < 0) rel += M;
            o[j] = (rel < B) ? aq : u[j];
        }
        __builtin_nontemporal_store(o, &out_util[i4]);
    } else if (blockIdx.x == MEM_BLOCKS - 1) {
        // ---- scalars: utilization + quality ----
        const float aq   = *aq_p;
        const int   nidx = (s + B) % M;
        const bool  full = (s + B) >= M;

        float local = 0.f;
        if (!full) {
            for (int i = threadIdx.x; i < s; i += THREADS)
                local += utilf[i];
        }
        for (int off = 32; off > 0; off >>= 1)
            local += __shfl_down(local, off, 64);
        __shared__ float wsum[THREADS / 64];
        if ((threadIdx.x & 63) == 0) wsum[threadIdx.x >> 6] = local;
        __syncthreads();
        if (threadIdx.x == 0) {
            float ssum = 0.f;
#pragma unroll
            for (int w = 0; w < THREADS / 64; ++w) ssum += wsum[w];
            float q;
            if (full) {
                // prefix [0:nidx) is entirely inside the written range
                q = (nidx > 0) ? aq : (0.0f / 0.0f);   // empty slice -> NaN
            } else {
                q = (ssum + (float)B * aq) / (float)(s + B);
            }
            out_scalars[0] = full ? 1.0f : (float)nidx / (float)M;
            out_scalars[1] = q;
        }
    }

    // ---- big streaming copy: exactly ITERS iterations, batched 8-wide ----
    const int tid  = blockIdx.x * THREADS + threadIdx.x;
    const int col  = tid & (D4 - 1);
    const int row0 = tid >> LOG_D4;
#pragma unroll
    for (int ib = 0; ib < ITERS / BATCH; ++ib) {
        f32x4 vals[BATCH];
#pragma unroll
        for (int j = 0; j < BATCH; ++j) {
            const int it  = ib * BATCH + j;
            const int row = row0 + it * ROWSTRIDE;
            int rel = row - s;
            if (rel < 0) rel += M;
            if (rel < B) {
                vals[j] = feat[(rel << LOG_D4) | col];
            } else {
                vals[j] = mem[tid + it * STRIDE];
            }
        }
#pragma unroll
        for (int j = 0; j < BATCH; ++j) {
            const int it = ib * BATCH + j;
            __builtin_nontemporal_store(vals[j], &out_mem[tid + it * STRIDE]);
        }
    }
}

// ---------------------------------------------------------------------------
extern "C" void kernel_launch(void* const* d_in, const int* in_sizes, int n_in,
                              void* d_out, int out_size, void* d_ws, size_t ws_size,
                              hipStream_t stream)
{
    const float* feat = (const float*)d_in[0];   // (B, D) f32
    const float* aq   = (const float*)d_in[1];   // scalar f32
    const float* mem  = (const float*)d_in[2];   // (M, D) f32
    const float* util = (const float*)d_in[3];   // (M,) f32
    const int*   mi   = (const int*)  d_in[4];   // scalar int

    float* out         = (float*)d_out;
    float* out_mem     = out;                    // M*D
    float* out_util    = out + (size_t)M * D;    // M
    float* out_scalars = out_util + M;           // [utilization, quality]

    fused_kernel<<<MEM_BLOCKS, THREADS, 0, stream>>>(
        (const f32x4*)mem, (const f32x4*)feat, (const f32x4*)util, util,
        aq, mi, (f32x4*)out_mem, (f32x4*)out_util, out_scalars);
}